// Round 5
// baseline (805.738 us; speedup 1.0000x reference)
//
#include <hip/hip_runtime.h>
#include <hip/hip_bf16.h>
#include <math.h>

// ---------------------------------------------------------------------------
// DeepSeek MLA forward. Round 14:
//  - Attribution across R9-R13: FETCH is 122 MB iff every staging load is
//    drained on the critical path (R9); ANY prefetch (R10 deep, R11 reg-
//    direct, R12/R13 1-ahead) -> 305-389 MB. The drain is the L2 convoy's
//    negative feedback: a leading block stalls on its own misses and falls
//    back into the pack. Prefetch hides the stall -> permanent desync.
//  - R14 = R12's 512-thread structure MINUS prefetch: stage chunk ->
//    __syncthreads (vmcnt0 drain) -> compute. One variable vs R12/R13.
//    2x TLP of R9 (16 waves/CU paired, 8 in solo tail), R12's conflict-free
//    Q/K LDS layouts, R13's coalesced epilogue. 9 barriers/k-tile.
//  - Everything else (GEMMs, cvt, transpose, mapping) unchanged.
// ---------------------------------------------------------------------------

#define T_DIM 2048
#define HEADS 16
#define D_MODEL 2048
#define NOPE_D 128
#define ROPE_D 64
#define QKD_D 192
#define VD_D 128
#define QLORA 768
#define KVLORA 512
#define KVFULL_D 576
#define SOFTSCALE -96.0f
#define EPS_RMS 1e-6f

typedef __hip_bfloat16 bf;
typedef __attribute__((ext_vector_type(8))) short bf16x8;
typedef __attribute__((ext_vector_type(4))) float f32x4;

#define GLOAD_LDS16(gptr, lptr)                                               \
    __builtin_amdgcn_global_load_lds(                                         \
        (const __attribute__((address_space(1))) unsigned int*)(gptr),        \
        (__attribute__((address_space(3))) unsigned int*)(lptr), 16, 0, 0)

__device__ __forceinline__ void split2(float v, bf* hi, bf* lo) {
    bf h = __float2bfloat16(v);
    *hi = h;
    *lo = __float2bfloat16(v - __bfloat162float(h));
}

// ---------------------------------------------------------------------------
__global__ __launch_bounds__(256) void cvt_split(
    const float* __restrict__ in, bf* __restrict__ hi, bf* __restrict__ lo, int n)
{
    const int i = (blockIdx.x * 256 + threadIdx.x) * 4;
    if (i >= n) return;
    float4 v = *(const float4*)&in[i];
    float vv[4] = {v.x, v.y, v.z, v.w};
#pragma unroll
    for (int u = 0; u < 4; u++) split2(vv[u], &hi[i + u], &lo[i + u]);
}

__global__ __launch_bounds__(256) void cvt_hi(
    const float* __restrict__ in, bf* __restrict__ hi, int n)
{
    const int i = (blockIdx.x * 256 + threadIdx.x) * 4;
    if (i >= n) return;
    float4 v = *(const float4*)&in[i];
    hi[i + 0] = __float2bfloat16(v.x);
    hi[i + 1] = __float2bfloat16(v.y);
    hi[i + 2] = __float2bfloat16(v.z);
    hi[i + 3] = __float2bfloat16(v.w);
}

// ---------------------------------------------------------------------------
__global__ __launch_bounds__(256) void rmsnorm_cvt(
    const float* __restrict__ in, int ld, int D, const float* __restrict__ w,
    bf* __restrict__ hi, bf* __restrict__ lo)
{
    const int row = blockIdx.x;
    const float* r = in + (size_t)row * ld;
    float ss = 0.0f;
    for (int i = threadIdx.x; i < D; i += 256) { float v = r[i]; ss += v * v; }
#pragma unroll
    for (int o = 32; o > 0; o >>= 1) ss += __shfl_down(ss, o, 64);
    __shared__ float red[4];
    if ((threadIdx.x & 63) == 0) red[threadIdx.x >> 6] = ss;
    __syncthreads();
    ss = red[0] + red[1] + red[2] + red[3];
    const float scale = rsqrtf(ss / (float)D + EPS_RMS);
    for (int i = threadIdx.x; i < D; i += 256) {
        const float v = r[i] * scale * w[i];
        split2(v, &hi[(size_t)row * D + i], &lo[(size_t)row * D + i]);
    }
}

// ---------------------------------------------------------------------------
__global__ __launch_bounds__(256) void rope_k_cvt(
    const float* __restrict__ kvfull, const float* __restrict__ freqs,
    bf* __restrict__ kpeh, bf* __restrict__ kpel)
{
    const int idx = blockIdx.x * 256 + threadIdx.x;   // 65536
    const int i = idx & 31, t = idx >> 5;
    const float f = freqs[t * 32 + i];
    float sn, cs; sincosf(f, &sn, &cs);
    const float x1 = kvfull[(size_t)t * KVFULL_D + KVLORA + 2 * i];
    const float x2 = kvfull[(size_t)t * KVFULL_D + KVLORA + 2 * i + 1];
    split2(x1 * cs - x2 * sn, &kpeh[t * 64 + 2 * i], &kpel[t * 64 + 2 * i]);
    split2(x1 * sn + x2 * cs, &kpeh[t * 64 + 2 * i + 1], &kpel[t * 64 + 2 * i + 1]);
}

// ---------------------------------------------------------------------------
__global__ __launch_bounds__(256) void transpose_v(
    const bf* __restrict__ vh, bf* __restrict__ vT)
{
    __shared__ bf s[32][33];
    const int t0 = blockIdx.x * 32, d0 = blockIdx.y * 32, h = blockIdx.z;
    const int tid = threadIdx.x;
    const int i = tid >> 3, j0 = (tid & 7) * 4;
    const bf* src = vh + ((size_t)(t0 + i) * 16 + h) * 128 + d0 + j0;
#pragma unroll
    for (int u = 0; u < 4; u++) s[i][j0 + u] = src[u];
    __syncthreads();
    const int jj = tid >> 3, i0 = (tid & 7) * 4;
    bf* dst = vT + ((size_t)h * 128 + d0 + jj) * 2048 + t0 + i0;
#pragma unroll
    for (int u = 0; u < 4; u++) dst[u] = s[i0 + u][jj];
}

// ---------------------------------------------------------------------------
// Split-bf16 GEMM (score path), 128x128 tile, 3 MFMAs.
// MODE 1: RoPE on d>=128 + split -> Oh/Ol (q). MODE 2: kn/v split write.
// ---------------------------------------------------------------------------
template <int MODE>
__global__ __launch_bounds__(256) void gemm_split(
    const bf* __restrict__ Ah, const bf* __restrict__ Al,
    const bf* __restrict__ Bh, const bf* __restrict__ Bl,
    const float* __restrict__ freqs,
    float* __restrict__ Cf, bf* __restrict__ Oh, bf* __restrict__ Ol,
    bf* __restrict__ O2, int M, int N, int K)
{
    __shared__ bf sAh[128 * 32], sAl[128 * 32];
    __shared__ bf sBh[128 * 32], sBl[128 * 32];

    const int tid = threadIdx.x;
    const int lane = tid & 63, wave = tid >> 6;
    const int row0 = blockIdx.y * 128, col0 = blockIdx.x * 128;
    const int wm = (wave & 1) * 64, wn = (wave >> 1) * 64;
    const int fr = lane & 15, quad = lane >> 4;

    f32x4 acc[4][4];
#pragma unroll
    for (int i = 0; i < 4; i++)
#pragma unroll
        for (int j = 0; j < 4; j++) acc[i][j] = (f32x4){0.f, 0.f, 0.f, 0.f};

    const int trow = tid >> 2;
    const int tcol = (tid & 3) * 8;
    const size_t ldsoff = (size_t)wave * 1024;

    for (int kt = 0; kt < K; kt += 32) {
        __syncthreads();
        GLOAD_LDS16(Ah + (size_t)(row0 + trow) * K + kt + tcol,      (char*)sAh + ldsoff);
        GLOAD_LDS16(Ah + (size_t)(row0 + 64 + trow) * K + kt + tcol, (char*)sAh + 4096 + ldsoff);
        GLOAD_LDS16(Al + (size_t)(row0 + trow) * K + kt + tcol,      (char*)sAl + ldsoff);
        GLOAD_LDS16(Al + (size_t)(row0 + 64 + trow) * K + kt + tcol, (char*)sAl + 4096 + ldsoff);
        GLOAD_LDS16(Bh + (size_t)(col0 + trow) * K + kt + tcol,      (char*)sBh + ldsoff);
        GLOAD_LDS16(Bh + (size_t)(col0 + 64 + trow) * K + kt + tcol, (char*)sBh + 4096 + ldsoff);
        GLOAD_LDS16(Bl + (size_t)(col0 + trow) * K + kt + tcol,      (char*)sBl + ldsoff);
        GLOAD_LDS16(Bl + (size_t)(col0 + 64 + trow) * K + kt + tcol, (char*)sBl + 4096 + ldsoff);
        __syncthreads();

        bf16x8 a_h[4], a_l[4], b_h[4], b_l[4];
#pragma unroll
        for (int mt = 0; mt < 4; mt++) {
            const int r = (wm + mt * 16 + fr) * 32 + quad * 8;
            a_h[mt] = *(const bf16x8*)&sAh[r];
            a_l[mt] = *(const bf16x8*)&sAl[r];
        }
#pragma unroll
        for (int nt = 0; nt < 4; nt++) {
            const int r = (wn + nt * 16 + fr) * 32 + quad * 8;
            b_h[nt] = *(const bf16x8*)&sBh[r];
            b_l[nt] = *(const bf16x8*)&sBl[r];
        }
#pragma unroll
        for (int mt = 0; mt < 4; mt++)
#pragma unroll
            for (int nt = 0; nt < 4; nt++) {
                acc[mt][nt] = __builtin_amdgcn_mfma_f32_16x16x32_bf16(
                    a_l[mt], b_h[nt], acc[mt][nt], 0, 0, 0);
                acc[mt][nt] = __builtin_amdgcn_mfma_f32_16x16x32_bf16(
                    a_h[mt], b_l[nt], acc[mt][nt], 0, 0, 0);
                acc[mt][nt] = __builtin_amdgcn_mfma_f32_16x16x32_bf16(
                    a_h[mt], b_h[nt], acc[mt][nt], 0, 0, 0);
            }
    }

#pragma unroll
    for (int mt = 0; mt < 4; mt++)
#pragma unroll
        for (int nt = 0; nt < 4; nt++) {
            const int colb = col0 + wn + nt * 16;
            const int col = colb + fr;
            if (MODE == 1) {
                const int d0 = colb % 192;
                const bool rope = (d0 >= 128);
                const int ii = (d0 + fr - 128) >> 1;
#pragma unroll
                for (int r = 0; r < 4; r++) {
                    const int row = row0 + wm + mt * 16 + quad * 4 + r;
                    float v = acc[mt][nt][r];
                    if (rope) {
                        const float other = __shfl_xor(v, 1);
                        float sn, cs; sincosf(freqs[row * 32 + ii], &sn, &cs);
                        v = (fr & 1) ? (other * sn + v * cs) : (v * cs - other * sn);
                    }
                    bf h8, l8; split2(v, &h8, &l8);
                    Oh[(size_t)row * N + col] = h8;
                    Ol[(size_t)row * N + col] = l8;
                }
            } else {
                const int hh = col >> 8;
                const int d = col & 255;
#pragma unroll
                for (int r = 0; r < 4; r++) {
                    const int row = row0 + wm + mt * 16 + quad * 4 + r;
                    const float v = acc[mt][nt][r];
                    if (d < 128) {
                        bf h8, l8; split2(v, &h8, &l8);
                        Oh[(size_t)row * 2048 + hh * 128 + d] = h8;
                        Ol[(size_t)row * 2048 + hh * 128 + d] = l8;
                    } else {
                        O2[(size_t)row * 2048 + hh * 128 + (d - 128)] = __float2bfloat16(v);
                    }
                }
            }
        }
}

// ---------------------------------------------------------------------------
// Split-bf16 GEMM, 64x64 tile (small-N shapes: qa N=768, kvfull N=576).
// ---------------------------------------------------------------------------
__global__ __launch_bounds__(256) void gemm_split64(
    const bf* __restrict__ Ah, const bf* __restrict__ Al,
    const bf* __restrict__ Bh, const bf* __restrict__ Bl,
    float* __restrict__ Cf, int M, int N, int K)
{
    __shared__ bf sAh[64 * 32], sAl[64 * 32];
    __shared__ bf sBh[64 * 32], sBl[64 * 32];

    const int tid = threadIdx.x;
    const int lane = tid & 63, wave = tid >> 6;
    const int row0 = blockIdx.y * 64, col0 = blockIdx.x * 64;
    const int wm = (wave & 1) * 32, wn = (wave >> 1) * 32;
    const int fr = lane & 15, quad = lane >> 4;

    f32x4 acc[2][2];
#pragma unroll
    for (int i = 0; i < 2; i++)
#pragma unroll
        for (int j = 0; j < 2; j++) acc[i][j] = (f32x4){0.f, 0.f, 0.f, 0.f};

    const int trow = tid >> 2;
    const int tcol = (tid & 3) * 8;
    const size_t ldsoff = (size_t)wave * 1024;

    for (int kt = 0; kt < K; kt += 32) {
        __syncthreads();
        GLOAD_LDS16(Ah + (size_t)(row0 + trow) * K + kt + tcol, (char*)sAh + ldsoff);
        GLOAD_LDS16(Al + (size_t)(row0 + trow) * K + kt + tcol, (char*)sAl + ldsoff);
        GLOAD_LDS16(Bh + (size_t)(col0 + trow) * K + kt + tcol, (char*)sBh + ldsoff);
        GLOAD_LDS16(Bl + (size_t)(col0 + trow) * K + kt + tcol, (char*)sBl + ldsoff);
        __syncthreads();

        bf16x8 a_h[2], a_l[2], b_h[2], b_l[2];
#pragma unroll
        for (int mt = 0; mt < 2; mt++) {
            const int r = (wm + mt * 16 + fr) * 32 + quad * 8;
            a_h[mt] = *(const bf16x8*)&sAh[r];
            a_l[mt] = *(const bf16x8*)&sAl[r];
        }
#pragma unroll
        for (int nt = 0; nt < 2; nt++) {
            const int r = (wn + nt * 16 + fr) * 32 + quad * 8;
            b_h[nt] = *(const bf16x8*)&sBh[r];
            b_l[nt] = *(const bf16x8*)&sBl[r];
        }
#pragma unroll
        for (int mt = 0; mt < 2; mt++)
#pragma unroll
            for (int nt = 0; nt < 2; nt++) {
                acc[mt][nt] = __builtin_amdgcn_mfma_f32_16x16x32_bf16(
                    a_l[mt], b_h[nt], acc[mt][nt], 0, 0, 0);
                acc[mt][nt] = __builtin_amdgcn_mfma_f32_16x16x32_bf16(
                    a_h[mt], b_l[nt], acc[mt][nt], 0, 0, 0);
                acc[mt][nt] = __builtin_amdgcn_mfma_f32_16x16x32_bf16(
                    a_h[mt], b_h[nt], acc[mt][nt], 0, 0, 0);
            }
    }

#pragma unroll
    for (int mt = 0; mt < 2; mt++)
#pragma unroll
        for (int nt = 0; nt < 2; nt++)
#pragma unroll
            for (int r = 0; r < 4; r++)
                Cf[(size_t)(row0 + wm + mt * 16 + quad * 4 + r) * N +
                   col0 + wn + nt * 16 + fr] = acc[mt][nt][r];
}

// ---------------------------------------------------------------------------
// Plain bf16 GEMM (post-softmax out-projection): C = A @ B^T, single MFMA.
// ---------------------------------------------------------------------------
__global__ __launch_bounds__(256) void gemm_bf16(
    const bf* __restrict__ Ah, const bf* __restrict__ Bh,
    float* __restrict__ Cf, int M, int N, int K)
{
    __shared__ bf sAh[128 * 32];
    __shared__ bf sBh[128 * 32];

    const int tid = threadIdx.x;
    const int lane = tid & 63, wave = tid >> 6;
    const int row0 = blockIdx.y * 128, col0 = blockIdx.x * 128;
    const int wm = (wave & 1) * 64, wn = (wave >> 1) * 64;
    const int fr = lane & 15, quad = lane >> 4;

    f32x4 acc[4][4];
#pragma unroll
    for (int i = 0; i < 4; i++)
#pragma unroll
        for (int j = 0; j < 4; j++) acc[i][j] = (f32x4){0.f, 0.f, 0.f, 0.f};

    const int trow = tid >> 2;
    const int tcol = (tid & 3) * 8;
    const size_t ldsoff = (size_t)wave * 1024;

    for (int kt = 0; kt < K; kt += 32) {
        __syncthreads();
        GLOAD_LDS16(Ah + (size_t)(row0 + trow) * K + kt + tcol,      (char*)sAh + ldsoff);
        GLOAD_LDS16(Ah + (size_t)(row0 + 64 + trow) * K + kt + tcol, (char*)sAh + 4096 + ldsoff);
        GLOAD_LDS16(Bh + (size_t)(col0 + trow) * K + kt + tcol,      (char*)sBh + ldsoff);
        GLOAD_LDS16(Bh + (size_t)(col0 + 64 + trow) * K + kt + tcol, (char*)sBh + 4096 + ldsoff);
        __syncthreads();

        bf16x8 a_h[4], b_h[4];
#pragma unroll
        for (int mt = 0; mt < 4; mt++)
            a_h[mt] = *(const bf16x8*)&sAh[(wm + mt * 16 + fr) * 32 + quad * 8];
#pragma unroll
        for (int nt = 0; nt < 4; nt++)
            b_h[nt] = *(const bf16x8*)&sBh[(wn + nt * 16 + fr) * 32 + quad * 8];
#pragma unroll
        for (int mt = 0; mt < 4; mt++)
#pragma unroll
            for (int nt = 0; nt < 4; nt++)
                acc[mt][nt] = __builtin_amdgcn_mfma_f32_16x16x32_bf16(
                    a_h[mt], b_h[nt], acc[mt][nt], 0, 0, 0);
    }

#pragma unroll
    for (int mt = 0; mt < 4; mt++)
#pragma unroll
        for (int nt = 0; nt < 4; nt++)
#pragma unroll
            for (int r = 0; r < 4; r++)
                Cf[(size_t)(row0 + wm + mt * 16 + quad * 4 + r) * N +
                   col0 + wn + nt * 16 + fr] = acc[mt][nt][r];
}

// ---------------------------------------------------------------------------
// 8-wave pure-drain monolithic MFMA flash attention. 512 blocks = (h, qt),
// heavy/light paired, sequential k. Per 32-dim chunk: stage -> __syncthreads
// (vmcnt0 drain = convoy feedback) -> compute. NO prefetch anywhere.
// LDS layouts conflict-free (R12): Q [4dg][64row][8], K [4dg][128key][8],
// V [4vc][4dg][128vd][8]. Ps[64][136]; coalesced y epilogue via Ps reuse.
// LDS: buf0@0, buf1@24576 (each 24 KB: Qh 4K/Ql 4K/Kh 8K/Kl 8K); sVt aliases
// smem[0..32K] during PV. Total 69 KB -> 2 blocks/CU.
// ---------------------------------------------------------------------------
#define STAGE_QK(buf_, k0_, d0_)                                              \
  do {                                                                        \
    if ((d0_) < 128) {                                                        \
      GLOAD_LDS16(knh + ((size_t)((k0_) + key) * 16 + h) * 128 + (d0_) + kdg, \
                  (buf_) + 8192 + loff);                                      \
      GLOAD_LDS16(knl + ((size_t)((k0_) + key) * 16 + h) * 128 + (d0_) + kdg, \
                  (buf_) + 16384 + loff);                                     \
    } else {                                                                  \
      GLOAD_LDS16(kpeh + (size_t)((k0_) + key) * 64 + (d0_) - 128 + kdg,      \
                  (buf_) + 8192 + loff);                                      \
      GLOAD_LDS16(kpel + (size_t)((k0_) + key) * 64 + (d0_) - 128 + kdg,      \
                  (buf_) + 16384 + loff);                                     \
    }                                                                         \
    GLOAD_LDS16(qsrc + ((size_t)(q0 + lane) * 16 + h) * 192 + (d0_) + qdg,    \
                (buf_) + loff);                                               \
  } while (0)

__global__ __launch_bounds__(512, 4) void attn_mfma(
    const bf* __restrict__ qh, const bf* __restrict__ ql,
    const bf* __restrict__ knh, const bf* __restrict__ knl,
    const bf* __restrict__ kpeh, const bf* __restrict__ kpel,
    const bf* __restrict__ vT, bf* __restrict__ yh)
{
    const int bid = blockIdx.x;
    const int h = bid & 15;
    const int qt = (bid < 256) ? (31 - (bid >> 4)) : ((bid - 256) >> 4);

    const int tid = threadIdx.x;
    const int lane = tid & 63, wave = tid >> 6;       // wave 0..7
    const int fr = lane & 15, quad = lane >> 4;
    const int wn = wave * 16;                         // 16 keys / V-dims per wave

    __shared__ __align__(16) char smem[49152];        // buf0 + buf1 (+ sVt alias)
    __shared__ __align__(16) bf Ps[64 * 136];
    __shared__ __align__(16) float redM[64 * 8];
    __shared__ __align__(16) float redS[64 * 8];

    float m_i[16], l_i[16];
    f32x4 O[4];
#pragma unroll
    for (int i = 0; i < 16; i++) { m_i[i] = -INFINITY; l_i[i] = 0.0f; }
#pragma unroll
    for (int mt = 0; mt < 4; mt++) O[mt] = (f32x4){0.f, 0.f, 0.f, 0.f};

    const int q0 = qt * 64;
    const int nkt = ((qt + 1) * 64 + 127) >> 7;
    const size_t loff = (size_t)wave * 1024;

    // staging decomposition (per thread):
    const int key = tid & 127;            // K subtile: row
    const int kdg = (tid >> 7) * 8;       // K subtile: dim-group offset
    const bf* qsrc = (wave < 4) ? qh : ql;
    const int qdg = (wave & 3) * 8;       // Q subtile: dim-group offset

    for (int kt = 0; kt < nkt; kt++) {
        const int k0 = kt * 128;
        f32x4 S[4];
#pragma unroll
        for (int mt = 0; mt < 4; mt++) S[mt] = (f32x4){0.f, 0.f, 0.f, 0.f};

        __syncthreads();                 // prior PV readers of smem done

        // ---- S = Q.K^T over 192 dims: 6 chunks, PURE DRAIN each ----
#pragma unroll
        for (int ch = 0; ch < 6; ch++) {
            char* buf = smem + ((ch & 1) ? 24576 : 0);
            STAGE_QK(buf, k0, ch * 32);
            __syncthreads();             // drain: loads land; convoy feedback

            const bf* sQh = (const bf*)buf;            // [4 dg][64 rows][8]
            const bf* sQl = (const bf*)(buf + 4096);
            const bf* sKh = (const bf*)(buf + 8192);   // [4 dg][128 keys][8]
            const bf* sKl = (const bf*)(buf + 16384);
            bf16x8 a_h[4], a_l[4], b_h, b_l;
#pragma unroll
            for (int mt = 0; mt < 4; mt++) {
                const int r = (quad * 64 + mt * 16 + fr) * 8;
                a_h[mt] = *(const bf16x8*)&sQh[r];
                a_l[mt] = *(const bf16x8*)&sQl[r];
            }
            {
                const int r = (quad * 128 + wn + fr) * 8;
                b_h = *(const bf16x8*)&sKh[r];
                b_l = *(const bf16x8*)&sKl[r];
            }
#pragma unroll
            for (int mt = 0; mt < 4; mt++) {
                S[mt] = __builtin_amdgcn_mfma_f32_16x16x32_bf16(a_l[mt], b_h, S[mt], 0, 0, 0);
                S[mt] = __builtin_amdgcn_mfma_f32_16x16x32_bf16(a_h[mt], b_l, S[mt], 0, 0, 0);
                S[mt] = __builtin_amdgcn_mfma_f32_16x16x32_bf16(a_h[mt], b_h, S[mt], 0, 0, 0);
            }
        }

        // ---- softmax part 1: scale, causal mask, wave row-max ----
#pragma unroll
        for (int mt = 0; mt < 4; mt++)
#pragma unroll
            for (int rr = 0; rr < 4; rr++) {
                const int ri = mt * 16 + quad * 4 + rr;
                const int rowg = q0 + ri;
                float v0 = S[mt][rr] * SOFTSCALE;
                if (k0 + wn + fr > rowg) v0 = -INFINITY;
                S[mt][rr] = v0;
                float pm = v0;
#pragma unroll
                for (int o = 1; o < 16; o <<= 1) pm = fmaxf(pm, __shfl_xor(pm, o, 64));
                if (fr == 0) redM[ri * 8 + wave] = pm;
            }
        __syncthreads();   // B1: redM visible; all chunk-5 buf readers done

        // ---- V stage into buf alias: [4 vc][4 dg][128 vd][8 keys] ----
#pragma unroll
        for (int i = 0; i < 4; i++) {
            const int N = i * 512 + tid;
            const int vc = N >> 9, dg = (N >> 7) & 3, vd = N & 127;
            GLOAD_LDS16(vT + ((size_t)(h * 128 + vd)) * 2048 + k0 + vc * 32 + dg * 8,
                        smem + i * 8192 + loff);
        }

        // ---- softmax part 2: exp, Ps write, wave row-sum ----
#pragma unroll
        for (int mt = 0; mt < 4; mt++)
#pragma unroll
            for (int rr = 0; rr < 4; rr++) {
                const int idx = mt * 4 + rr;
                const int ri = mt * 16 + quad * 4 + rr;
                const float4 g0 = *(const float4*)&redM[ri * 8];
                const float4 g1 = *(const float4*)&redM[ri * 8 + 4];
                float gm = fmaxf(fmaxf(fmaxf(g0.x, g0.y), fmaxf(g0.z, g0.w)),
                                 fmaxf(fmaxf(g1.x, g1.y), fmaxf(g1.z, g1.w)));
                const float mn = fmaxf(m_i[idx], gm);
                const float al = __expf(m_i[idx] - mn);
                m_i[idx] = mn;
                l_i[idx] *= al;
                O[mt][rr] *= al;
                const float p0 = __expf(S[mt][rr] - mn);
                Ps[ri * 136 + wn + fr] = __float2bfloat16(p0);
                float ps = p0;
#pragma unroll
                for (int o = 1; o < 16; o <<= 1) ps += __shfl_xor(ps, o, 64);
                if (fr == 0) redS[ri * 8 + wave] = ps;
            }
        __syncthreads();   // B2: Ps/redS visible; V landed (full drain)

#pragma unroll
        for (int mt = 0; mt < 4; mt++)
#pragma unroll
            for (int rr = 0; rr < 4; rr++) {
                const int ri = mt * 16 + quad * 4 + rr;
                const float4 s0 = *(const float4*)&redS[ri * 8];
                const float4 s1 = *(const float4*)&redS[ri * 8 + 4];
                l_i[mt * 4 + rr] += (s0.x + s0.y + s0.z + s0.w) +
                                    (s1.x + s1.y + s1.z + s1.w);
            }

        // ---- PV: O += P @ V over 128 keys (4 chunks of 32) ----
        const bf* sV = (const bf*)smem;
#pragma unroll
        for (int vc = 0; vc < 4; vc++) {
            bf16x8 ap[4], bv;
#pragma unroll
            for (int mt = 0; mt < 4; mt++)
                ap[mt] = *(const bf16x8*)&Ps[(mt * 16 + fr) * 136 + vc * 32 + quad * 8];
            bv = *(const bf16x8*)&sV[((vc * 4 + quad) * 128 + wn + fr) * 8];
#pragma unroll
            for (int mt = 0; mt < 4; mt++)
                O[mt] = __builtin_amdgcn_mfma_f32_16x16x32_bf16(ap[mt], bv, O[mt], 0, 0, 0);
        }
    }

    // ---- epilogue: y = O / l via LDS transpose -> coalesced 16B writes ----
    __syncthreads();                       // all waves' PV Ps-reads done
#pragma unroll
    for (int mt = 0; mt < 4; mt++)
#pragma unroll
        for (int rr = 0; rr < 4; rr++) {
            const float inv = 1.0f / l_i[mt * 4 + rr];
            const int ri = mt * 16 + quad * 4 + rr;
            Ps[ri * 128 + wn + fr] = __float2bfloat16(O[mt][rr] * inv);
        }
    __syncthreads();
    {
        const int r = tid >> 3;            // 64 rows, 8 threads/row
        const int c = (tid & 7) * 16;      // each thread: 2 x 16B chunks
        bf* dst = &yh[((size_t)(q0 + r) * 16 + h) * 128 + c];
        *(bf16x8*)dst       = *(const bf16x8*)&Ps[r * 128 + c];
        *(bf16x8*)(dst + 8) = *(const bf16x8*)&Ps[r * 128 + c + 8];
    }
}

// ---------------------------------------------------------------------------
// Workspace (peak < 85 MB):
//  A  @0        : xh(8.39) xl(8.39) -> yh@0, vT@8.39
//  AR @16.78    : (16.78) GEMM temporaries -> woh
//  persistent   : qh@33.55 ql@46.14 knh@58.72 knl@67.11 vh@75.50
//                 kpeh@83.89 kpel@84.15
// ---------------------------------------------------------------------------
extern "C" void kernel_launch(void* const* d_in, const int* in_sizes, int n_in,
                              void* d_out, int out_size, void* d_ws, size_t ws_size,
                              hipStream_t stream)
{
    const float* x        = (const float*)d_in[0];
    const float* freqs    = (const float*)d_in[1];
    const float* wq_a     = (const float*)d_in[3];
    const float* q_norm_w = (const float*)d_in[4];
    const float* wq_b     = (const float*)d_in[5];
    const float* wkv_a    = (const float*)d_in[6];
    const float* kv_norm_w= (const float*)d_in[7];
    const float* wkv_b    = (const float*)d_in[8];
    const float* wo       = (const float*)d_in[9];
    float* out            = (float*)d_out;

    char* ws = (char*)d_ws;
    bf* xh = (bf*)(ws);
    bf* xl = (bf*)(ws + 8388608);
    bf* yh = (bf*)(ws);                   // after x dead
    bf* vT = (bf*)(ws + 8388608);         // after x dead
    char* AR = ws + 16777216;
    bf*    wah    = (bf*)(AR);
    bf*    wal    = (bf*)(AR + 3145728);
    float* qa     = (float*)(AR + 6291456);
    bf*    qah    = (bf*)(AR);
    bf*    qal    = (bf*)(AR + 3145728);
    bf*    wbh    = (bf*)(AR + 6291456);
    bf*    wbl    = (bf*)(AR + 11010048);
    bf*    kah    = (bf*)(AR);
    bf*    kal    = (bf*)(AR + 2359296);
    float* kvfull = (float*)(AR + 4718592);
    bf*    ckvh   = (bf*)(AR + 9437184);
    bf*    ckvl   = (bf*)(AR + 11534336);
    bf*    wvh    = (bf*)(AR);
    bf*    wvl    = (bf*)(AR + 4194304);
    bf*    woh    = (bf*)(AR);
    bf* qh   = (bf*)(ws + 33554432);
    bf* ql   = (bf*)(ws + 46137344);
    bf* knh  = (bf*)(ws + 58720256);
    bf* knl  = (bf*)(ws + 67108864);
    bf* vh   = (bf*)(ws + 75497472);
    bf* kpeh = (bf*)(ws + 83886080);
    bf* kpel = (bf*)(ws + 84148224);

    dim3 blk(256);

    cvt_split<<<4096, blk, 0, stream>>>(x, xh, xl, D_MODEL * D_MODEL);
    cvt_split<<<1536, blk, 0, stream>>>(wq_a, wah, wal, QLORA * D_MODEL);
    gemm_split64<<<dim3(12, 32), blk, 0, stream>>>(
        xh, xl, wah, wal, qa, T_DIM, QLORA, D_MODEL);
    rmsnorm_cvt<<<T_DIM, blk, 0, stream>>>(qa, QLORA, QLORA, q_norm_w, qah, qal);
    cvt_split<<<2304, blk, 0, stream>>>(wq_b, wbh, wbl, 3072 * QLORA);
    gemm_split<1><<<dim3(24, 16), blk, 0, stream>>>(
        qah, qal, wbh, wbl, freqs, nullptr, qh, ql, nullptr,
        T_DIM, 3072, QLORA);
    cvt_split<<<1152, blk, 0, stream>>>(wkv_a, kah, kal, KVFULL_D * D_MODEL);
    gemm_split64<<<dim3(9, 32), blk, 0, stream>>>(
        xh, xl, kah, kal, kvfull, T_DIM, KVFULL_D, D_MODEL);
    rope_k_cvt<<<256, blk, 0, stream>>>(kvfull, freqs, kpeh, kpel);
    rmsnorm_cvt<<<T_DIM, blk, 0, stream>>>(kvfull, KVFULL_D, KVLORA, kv_norm_w, ckvh, ckvl);
    cvt_split<<<2048, blk, 0, stream>>>(wkv_b, wvh, wvl, 4096 * KVLORA);
    gemm_split<2><<<dim3(32, 16), blk, 0, stream>>>(
        ckvh, ckvl, wvh, wvl, nullptr, nullptr, knh, knl, vh,
        T_DIM, 4096, KVLORA);
    transpose_v<<<dim3(64, 4, 16), blk, 0, stream>>>(vh, vT);
    attn_mfma<<<dim3(512), dim3(512), 0, stream>>>(
        qh, ql, knh, knl, kpeh, kpel, vT, yh);
    cvt_hi<<<4096, blk, 0, stream>>>(wo, woh, D_MODEL * D_MODEL);
    gemm_bf16<<<dim3(16, 16), blk, 0, stream>>>(
        yh, woh, out, T_DIM, D_MODEL, D_MODEL);
}

// Round 6
// 627.700 us; speedup vs baseline: 1.2836x; 1.2836x over previous
//
#include <hip/hip_runtime.h>
#include <hip/hip_bf16.h>
#include <math.h>

// ---------------------------------------------------------------------------
// DeepSeek MLA forward. Round 15:
//  - R10-R14 post-mortem: five attn restructurings all tripled FETCH
//    (305-389 MB vs R9's 122) despite identical static access patterns;
//    the R9 kernel's temporal L2 reuse is not reproducible by design-level
//    reasoning. REVERT attn_mfma byte-for-byte to R9 (265 us, known good).
//  - This round's change: BK 32->64 for the three deep-K (K=2048) GEMMs
//    (gemm_split64 x2, gemm_bf16): halves the 64-iteration drain-barrier
//    count at identical staged bytes and bitwise-identical accumulation
//    order. LDS 16->32 KB each (still >=4 blocks/CU).
//  - Everything else byte-identical to the R9 baseline.
// ---------------------------------------------------------------------------

#define T_DIM 2048
#define HEADS 16
#define D_MODEL 2048
#define NOPE_D 128
#define ROPE_D 64
#define QKD_D 192
#define VD_D 128
#define QLORA 768
#define KVLORA 512
#define KVFULL_D 576
#define SOFTSCALE -96.0f
#define EPS_RMS 1e-6f

typedef __hip_bfloat16 bf;
typedef __attribute__((ext_vector_type(8))) short bf16x8;
typedef __attribute__((ext_vector_type(4))) float f32x4;

#define GLOAD_LDS16(gptr, lptr)                                               \
    __builtin_amdgcn_global_load_lds(                                         \
        (const __attribute__((address_space(1))) unsigned int*)(gptr),        \
        (__attribute__((address_space(3))) unsigned int*)(lptr), 16, 0, 0)

__device__ __forceinline__ void split2(float v, bf* hi, bf* lo) {
    bf h = __float2bfloat16(v);
    *hi = h;
    *lo = __float2bfloat16(v - __bfloat162float(h));
}

// ---------------------------------------------------------------------------
__global__ __launch_bounds__(256) void cvt_split(
    const float* __restrict__ in, bf* __restrict__ hi, bf* __restrict__ lo, int n)
{
    const int i = (blockIdx.x * 256 + threadIdx.x) * 4;
    if (i >= n) return;
    float4 v = *(const float4*)&in[i];
    float vv[4] = {v.x, v.y, v.z, v.w};
#pragma unroll
    for (int u = 0; u < 4; u++) split2(vv[u], &hi[i + u], &lo[i + u]);
}

__global__ __launch_bounds__(256) void cvt_hi(
    const float* __restrict__ in, bf* __restrict__ hi, int n)
{
    const int i = (blockIdx.x * 256 + threadIdx.x) * 4;
    if (i >= n) return;
    float4 v = *(const float4*)&in[i];
    hi[i + 0] = __float2bfloat16(v.x);
    hi[i + 1] = __float2bfloat16(v.y);
    hi[i + 2] = __float2bfloat16(v.z);
    hi[i + 3] = __float2bfloat16(v.w);
}

// ---------------------------------------------------------------------------
__global__ __launch_bounds__(256) void rmsnorm_cvt(
    const float* __restrict__ in, int ld, int D, const float* __restrict__ w,
    bf* __restrict__ hi, bf* __restrict__ lo)
{
    const int row = blockIdx.x;
    const float* r = in + (size_t)row * ld;
    float ss = 0.0f;
    for (int i = threadIdx.x; i < D; i += 256) { float v = r[i]; ss += v * v; }
#pragma unroll
    for (int o = 32; o > 0; o >>= 1) ss += __shfl_down(ss, o, 64);
    __shared__ float red[4];
    if ((threadIdx.x & 63) == 0) red[threadIdx.x >> 6] = ss;
    __syncthreads();
    ss = red[0] + red[1] + red[2] + red[3];
    const float scale = rsqrtf(ss / (float)D + EPS_RMS);
    for (int i = threadIdx.x; i < D; i += 256) {
        const float v = r[i] * scale * w[i];
        split2(v, &hi[(size_t)row * D + i], &lo[(size_t)row * D + i]);
    }
}

// ---------------------------------------------------------------------------
__global__ __launch_bounds__(256) void rope_k_cvt(
    const float* __restrict__ kvfull, const float* __restrict__ freqs,
    bf* __restrict__ kpeh, bf* __restrict__ kpel)
{
    const int idx = blockIdx.x * 256 + threadIdx.x;   // 65536
    const int i = idx & 31, t = idx >> 5;
    const float f = freqs[t * 32 + i];
    float sn, cs; sincosf(f, &sn, &cs);
    const float x1 = kvfull[(size_t)t * KVFULL_D + KVLORA + 2 * i];
    const float x2 = kvfull[(size_t)t * KVFULL_D + KVLORA + 2 * i + 1];
    split2(x1 * cs - x2 * sn, &kpeh[t * 64 + 2 * i], &kpel[t * 64 + 2 * i]);
    split2(x1 * sn + x2 * cs, &kpeh[t * 64 + 2 * i + 1], &kpel[t * 64 + 2 * i + 1]);
}

// ---------------------------------------------------------------------------
__global__ __launch_bounds__(256) void transpose_v(
    const bf* __restrict__ vh, bf* __restrict__ vT)
{
    __shared__ bf s[32][33];
    const int t0 = blockIdx.x * 32, d0 = blockIdx.y * 32, h = blockIdx.z;
    const int tid = threadIdx.x;
    const int i = tid >> 3, j0 = (tid & 7) * 4;
    const bf* src = vh + ((size_t)(t0 + i) * 16 + h) * 128 + d0 + j0;
#pragma unroll
    for (int u = 0; u < 4; u++) s[i][j0 + u] = src[u];
    __syncthreads();
    const int jj = tid >> 3, i0 = (tid & 7) * 4;
    bf* dst = vT + ((size_t)h * 128 + d0 + jj) * 2048 + t0 + i0;
#pragma unroll
    for (int u = 0; u < 4; u++) dst[u] = s[i0 + u][jj];
}

// ---------------------------------------------------------------------------
// Split-bf16 GEMM (score path), 128x128 tile, 3 MFMAs.
// MODE 1: RoPE on d>=128 + split -> Oh/Ol (q). MODE 2: kn/v split write.
// ---------------------------------------------------------------------------
template <int MODE>
__global__ __launch_bounds__(256) void gemm_split(
    const bf* __restrict__ Ah, const bf* __restrict__ Al,
    const bf* __restrict__ Bh, const bf* __restrict__ Bl,
    const float* __restrict__ freqs,
    float* __restrict__ Cf, bf* __restrict__ Oh, bf* __restrict__ Ol,
    bf* __restrict__ O2, int M, int N, int K)
{
    __shared__ bf sAh[128 * 32], sAl[128 * 32];
    __shared__ bf sBh[128 * 32], sBl[128 * 32];

    const int tid = threadIdx.x;
    const int lane = tid & 63, wave = tid >> 6;
    const int row0 = blockIdx.y * 128, col0 = blockIdx.x * 128;
    const int wm = (wave & 1) * 64, wn = (wave >> 1) * 64;
    const int fr = lane & 15, quad = lane >> 4;

    f32x4 acc[4][4];
#pragma unroll
    for (int i = 0; i < 4; i++)
#pragma unroll
        for (int j = 0; j < 4; j++) acc[i][j] = (f32x4){0.f, 0.f, 0.f, 0.f};

    const int trow = tid >> 2;
    const int tcol = (tid & 3) * 8;
    const size_t ldsoff = (size_t)wave * 1024;

    for (int kt = 0; kt < K; kt += 32) {
        __syncthreads();
        GLOAD_LDS16(Ah + (size_t)(row0 + trow) * K + kt + tcol,      (char*)sAh + ldsoff);
        GLOAD_LDS16(Ah + (size_t)(row0 + 64 + trow) * K + kt + tcol, (char*)sAh + 4096 + ldsoff);
        GLOAD_LDS16(Al + (size_t)(row0 + trow) * K + kt + tcol,      (char*)sAl + ldsoff);
        GLOAD_LDS16(Al + (size_t)(row0 + 64 + trow) * K + kt + tcol, (char*)sAl + 4096 + ldsoff);
        GLOAD_LDS16(Bh + (size_t)(col0 + trow) * K + kt + tcol,      (char*)sBh + ldsoff);
        GLOAD_LDS16(Bh + (size_t)(col0 + 64 + trow) * K + kt + tcol, (char*)sBh + 4096 + ldsoff);
        GLOAD_LDS16(Bl + (size_t)(col0 + trow) * K + kt + tcol,      (char*)sBl + ldsoff);
        GLOAD_LDS16(Bl + (size_t)(col0 + 64 + trow) * K + kt + tcol, (char*)sBl + 4096 + ldsoff);
        __syncthreads();

        bf16x8 a_h[4], a_l[4], b_h[4], b_l[4];
#pragma unroll
        for (int mt = 0; mt < 4; mt++) {
            const int r = (wm + mt * 16 + fr) * 32 + quad * 8;
            a_h[mt] = *(const bf16x8*)&sAh[r];
            a_l[mt] = *(const bf16x8*)&sAl[r];
        }
#pragma unroll
        for (int nt = 0; nt < 4; nt++) {
            const int r = (wn + nt * 16 + fr) * 32 + quad * 8;
            b_h[nt] = *(const bf16x8*)&sBh[r];
            b_l[nt] = *(const bf16x8*)&sBl[r];
        }
#pragma unroll
        for (int mt = 0; mt < 4; mt++)
#pragma unroll
            for (int nt = 0; nt < 4; nt++) {
                acc[mt][nt] = __builtin_amdgcn_mfma_f32_16x16x32_bf16(
                    a_l[mt], b_h[nt], acc[mt][nt], 0, 0, 0);
                acc[mt][nt] = __builtin_amdgcn_mfma_f32_16x16x32_bf16(
                    a_h[mt], b_l[nt], acc[mt][nt], 0, 0, 0);
                acc[mt][nt] = __builtin_amdgcn_mfma_f32_16x16x32_bf16(
                    a_h[mt], b_h[nt], acc[mt][nt], 0, 0, 0);
            }
    }

#pragma unroll
    for (int mt = 0; mt < 4; mt++)
#pragma unroll
        for (int nt = 0; nt < 4; nt++) {
            const int colb = col0 + wn + nt * 16;
            const int col = colb + fr;
            if (MODE == 1) {
                const int d0 = colb % 192;
                const bool rope = (d0 >= 128);
                const int ii = (d0 + fr - 128) >> 1;
#pragma unroll
                for (int r = 0; r < 4; r++) {
                    const int row = row0 + wm + mt * 16 + quad * 4 + r;
                    float v = acc[mt][nt][r];
                    if (rope) {
                        const float other = __shfl_xor(v, 1);
                        float sn, cs; sincosf(freqs[row * 32 + ii], &sn, &cs);
                        v = (fr & 1) ? (other * sn + v * cs) : (v * cs - other * sn);
                    }
                    bf h8, l8; split2(v, &h8, &l8);
                    Oh[(size_t)row * N + col] = h8;
                    Ol[(size_t)row * N + col] = l8;
                }
            } else {
                const int hh = col >> 8;
                const int d = col & 255;
#pragma unroll
                for (int r = 0; r < 4; r++) {
                    const int row = row0 + wm + mt * 16 + quad * 4 + r;
                    const float v = acc[mt][nt][r];
                    if (d < 128) {
                        bf h8, l8; split2(v, &h8, &l8);
                        Oh[(size_t)row * 2048 + hh * 128 + d] = h8;
                        Ol[(size_t)row * 2048 + hh * 128 + d] = l8;
                    } else {
                        O2[(size_t)row * 2048 + hh * 128 + (d - 128)] = __float2bfloat16(v);
                    }
                }
            }
        }
}

// ---------------------------------------------------------------------------
// Split-bf16 GEMM, 64x64 tile, BK=64 (R15): halves drain-barrier count on the
// two K=2048 shapes (qa N=768, kvfull N=576). LDS [2 ks][64][32] per array.
// Accumulation order identical to BK=32 version (same 32-dim chunk sequence).
// ---------------------------------------------------------------------------
__global__ __launch_bounds__(256) void gemm_split64(
    const bf* __restrict__ Ah, const bf* __restrict__ Al,
    const bf* __restrict__ Bh, const bf* __restrict__ Bl,
    float* __restrict__ Cf, int M, int N, int K)
{
    __shared__ bf sAh[2 * 64 * 32], sAl[2 * 64 * 32];
    __shared__ bf sBh[2 * 64 * 32], sBl[2 * 64 * 32];

    const int tid = threadIdx.x;
    const int lane = tid & 63, wave = tid >> 6;
    const int row0 = blockIdx.y * 64, col0 = blockIdx.x * 64;
    const int wm = (wave & 1) * 32, wn = (wave >> 1) * 32;
    const int fr = lane & 15, quad = lane >> 4;

    f32x4 acc[2][2];
#pragma unroll
    for (int i = 0; i < 2; i++)
#pragma unroll
        for (int j = 0; j < 2; j++) acc[i][j] = (f32x4){0.f, 0.f, 0.f, 0.f};

    const int trow = tid >> 2;
    const int tcol = (tid & 3) * 8;
    const size_t ldsoff = (size_t)wave * 1024;

    for (int kt = 0; kt < K; kt += 64) {
        __syncthreads();
        GLOAD_LDS16(Ah + (size_t)(row0 + trow) * K + kt + tcol,      (char*)sAh + ldsoff);
        GLOAD_LDS16(Ah + (size_t)(row0 + trow) * K + kt + 32 + tcol, (char*)sAh + 4096 + ldsoff);
        GLOAD_LDS16(Al + (size_t)(row0 + trow) * K + kt + tcol,      (char*)sAl + ldsoff);
        GLOAD_LDS16(Al + (size_t)(row0 + trow) * K + kt + 32 + tcol, (char*)sAl + 4096 + ldsoff);
        GLOAD_LDS16(Bh + (size_t)(col0 + trow) * K + kt + tcol,      (char*)sBh + ldsoff);
        GLOAD_LDS16(Bh + (size_t)(col0 + trow) * K + kt + 32 + tcol, (char*)sBh + 4096 + ldsoff);
        GLOAD_LDS16(Bl + (size_t)(col0 + trow) * K + kt + tcol,      (char*)sBl + ldsoff);
        GLOAD_LDS16(Bl + (size_t)(col0 + trow) * K + kt + 32 + tcol, (char*)sBl + 4096 + ldsoff);
        __syncthreads();

#pragma unroll
        for (int ks = 0; ks < 2; ks++) {
            bf16x8 a_h[2], a_l[2], b_h[2], b_l[2];
#pragma unroll
            for (int mt = 0; mt < 2; mt++) {
                const int r = ks * 2048 + (wm + mt * 16 + fr) * 32 + quad * 8;
                a_h[mt] = *(const bf16x8*)&sAh[r];
                a_l[mt] = *(const bf16x8*)&sAl[r];
            }
#pragma unroll
            for (int nt = 0; nt < 2; nt++) {
                const int r = ks * 2048 + (wn + nt * 16 + fr) * 32 + quad * 8;
                b_h[nt] = *(const bf16x8*)&sBh[r];
                b_l[nt] = *(const bf16x8*)&sBl[r];
            }
#pragma unroll
            for (int mt = 0; mt < 2; mt++)
#pragma unroll
                for (int nt = 0; nt < 2; nt++) {
                    acc[mt][nt] = __builtin_amdgcn_mfma_f32_16x16x32_bf16(
                        a_l[mt], b_h[nt], acc[mt][nt], 0, 0, 0);
                    acc[mt][nt] = __builtin_amdgcn_mfma_f32_16x16x32_bf16(
                        a_h[mt], b_l[nt], acc[mt][nt], 0, 0, 0);
                    acc[mt][nt] = __builtin_amdgcn_mfma_f32_16x16x32_bf16(
                        a_h[mt], b_h[nt], acc[mt][nt], 0, 0, 0);
                }
        }
    }

#pragma unroll
    for (int mt = 0; mt < 2; mt++)
#pragma unroll
        for (int nt = 0; nt < 2; nt++)
#pragma unroll
            for (int r = 0; r < 4; r++)
                Cf[(size_t)(row0 + wm + mt * 16 + quad * 4 + r) * N +
                   col0 + wn + nt * 16 + fr] = acc[mt][nt][r];
}

// ---------------------------------------------------------------------------
// Plain bf16 GEMM (post-softmax out-projection): C = A @ B^T, single MFMA.
// BK=64 (R15): halves drain-barrier count (K=2048). LDS [2 ks][128][32]/array.
// ---------------------------------------------------------------------------
__global__ __launch_bounds__(256) void gemm_bf16(
    const bf* __restrict__ Ah, const bf* __restrict__ Bh,
    float* __restrict__ Cf, int M, int N, int K)
{
    __shared__ bf sAh[2 * 128 * 32];
    __shared__ bf sBh[2 * 128 * 32];

    const int tid = threadIdx.x;
    const int lane = tid & 63, wave = tid >> 6;
    const int row0 = blockIdx.y * 128, col0 = blockIdx.x * 128;
    const int wm = (wave & 1) * 64, wn = (wave >> 1) * 64;
    const int fr = lane & 15, quad = lane >> 4;

    f32x4 acc[4][4];
#pragma unroll
    for (int i = 0; i < 4; i++)
#pragma unroll
        for (int j = 0; j < 4; j++) acc[i][j] = (f32x4){0.f, 0.f, 0.f, 0.f};

    const int trow = tid >> 2;
    const int tcol = (tid & 3) * 8;
    const size_t ldsoff = (size_t)wave * 1024;

    for (int kt = 0; kt < K; kt += 64) {
        __syncthreads();
        GLOAD_LDS16(Ah + (size_t)(row0 + trow) * K + kt + tcol,           (char*)sAh + ldsoff);
        GLOAD_LDS16(Ah + (size_t)(row0 + 64 + trow) * K + kt + tcol,      (char*)sAh + 4096 + ldsoff);
        GLOAD_LDS16(Ah + (size_t)(row0 + trow) * K + kt + 32 + tcol,      (char*)sAh + 8192 + ldsoff);
        GLOAD_LDS16(Ah + (size_t)(row0 + 64 + trow) * K + kt + 32 + tcol, (char*)sAh + 12288 + ldsoff);
        GLOAD_LDS16(Bh + (size_t)(col0 + trow) * K + kt + tcol,           (char*)sBh + ldsoff);
        GLOAD_LDS16(Bh + (size_t)(col0 + 64 + trow) * K + kt + tcol,      (char*)sBh + 4096 + ldsoff);
        GLOAD_LDS16(Bh + (size_t)(col0 + trow) * K + kt + 32 + tcol,      (char*)sBh + 8192 + ldsoff);
        GLOAD_LDS16(Bh + (size_t)(col0 + 64 + trow) * K + kt + 32 + tcol, (char*)sBh + 12288 + ldsoff);
        __syncthreads();

#pragma unroll
        for (int ks = 0; ks < 2; ks++) {
            bf16x8 a_h[4], b_h[4];
#pragma unroll
            for (int mt = 0; mt < 4; mt++)
                a_h[mt] = *(const bf16x8*)&sAh[ks * 4096 + (wm + mt * 16 + fr) * 32 + quad * 8];
#pragma unroll
            for (int nt = 0; nt < 4; nt++)
                b_h[nt] = *(const bf16x8*)&sBh[ks * 4096 + (wn + nt * 16 + fr) * 32 + quad * 8];
#pragma unroll
            for (int mt = 0; mt < 4; mt++)
#pragma unroll
                for (int nt = 0; nt < 4; nt++)
                    acc[mt][nt] = __builtin_amdgcn_mfma_f32_16x16x32_bf16(
                        a_h[mt], b_h[nt], acc[mt][nt], 0, 0, 0);
        }
    }

#pragma unroll
    for (int mt = 0; mt < 4; mt++)
#pragma unroll
        for (int nt = 0; nt < 4; nt++)
#pragma unroll
            for (int r = 0; r < 4; r++)
                Cf[(size_t)(row0 + wm + mt * 16 + quad * 4 + r) * N +
                   col0 + wn + nt * 16 + fr] = acc[mt][nt][r];
}

// ---------------------------------------------------------------------------
// Monolithic MFMA flash attention (EXACT R9 revert). 512 blocks = (h, qt),
// heavy/light paired. Per 128-key k-tile: ping-pong staged S (6 chunks x 1
// barrier), fp32 online softmax, PV with padded Ps (stride 72) + preloaded V
// pairs. Writes y bf16. LDS 60.4 KB -> 2 blocks/CU. (256,2).
// ---------------------------------------------------------------------------
__global__ __launch_bounds__(256, 2) void attn_mfma(
    const bf* __restrict__ qh, const bf* __restrict__ ql,
    const bf* __restrict__ knh, const bf* __restrict__ knl,
    const bf* __restrict__ kpeh, const bf* __restrict__ kpel,
    const bf* __restrict__ vT, bf* __restrict__ yh)
{
    const int bid = blockIdx.x;
    const int h = bid & 15;
    const int qt = (bid < 256) ? (31 - (bid >> 4)) : ((bid - 256) >> 4);

    const int tid = threadIdx.x;
    const int lane = tid & 63, wave = tid >> 6;
    const int fr = lane & 15, quad = lane >> 4;
    const int wn = wave * 32;

    // buf0 @0, buf1 @24576 (each: Qh 0 / Ql 4096 / Kh 8192 / Kl 16384)
    // sVt aliases buf0[0:16384] during PV. Ps @49152 ([64][72] bf16).
    __shared__ __align__(16) char smem[60416];
    bf* Ps  = (bf*)(smem + 49152);
    float* redM = (float*)(smem + 58368); // [64][4]
    float* redS = (float*)(smem + 59392); // [64][4]

    float m_i[16], l_i[16], al[16];
    f32x4 O[4][2];
#pragma unroll
    for (int i = 0; i < 16; i++) { m_i[i] = -INFINITY; l_i[i] = 0.0f; }
#pragma unroll
    for (int mt = 0; mt < 4; mt++)
#pragma unroll
        for (int nt = 0; nt < 2; nt++) O[mt][nt] = (f32x4){0.f, 0.f, 0.f, 0.f};

    const int q0 = qt * 64;
    const int nkt = ((qt + 1) * 64 + 127) >> 7;
    const int trow = tid >> 2, tcol = (tid & 3) * 8;
    const size_t loff = (size_t)wave * 1024;

    for (int kt = 0; kt < nkt; kt++) {
        const int k0 = kt * 128;
        f32x4 S[4][2];
#pragma unroll
        for (int mt = 0; mt < 4; mt++)
#pragma unroll
            for (int nt = 0; nt < 2; nt++) S[mt][nt] = (f32x4){0.f, 0.f, 0.f, 0.f};

        // leading barrier: prior k-tile's PV readers of buf0 (sVt alias) done
        __syncthreads();

        // ---- S = Q.K^T over 192 dims: 6 chunks, ping-pong, 1 barrier each --
        for (int ch = 0; ch < 6; ch++) {
            const int d0 = ch * 32;
            char* buf = smem + ((ch & 1) ? 24576 : 0);
            GLOAD_LDS16(qh + ((size_t)(q0 + trow) * 16 + h) * 192 + d0 + tcol, buf + loff);
            GLOAD_LDS16(ql + ((size_t)(q0 + trow) * 16 + h) * 192 + d0 + tcol, buf + 4096 + loff);
            if (d0 < 128) {
                GLOAD_LDS16(knh + ((size_t)(k0 + trow) * 16 + h) * 128 + d0 + tcol,      buf + 8192 + loff);
                GLOAD_LDS16(knh + ((size_t)(k0 + 64 + trow) * 16 + h) * 128 + d0 + tcol, buf + 12288 + loff);
                GLOAD_LDS16(knl + ((size_t)(k0 + trow) * 16 + h) * 128 + d0 + tcol,      buf + 16384 + loff);
                GLOAD_LDS16(knl + ((size_t)(k0 + 64 + trow) * 16 + h) * 128 + d0 + tcol, buf + 20480 + loff);
            } else {
                GLOAD_LDS16(kpeh + (size_t)(k0 + trow) * 64 + (d0 - 128) + tcol,      buf + 8192 + loff);
                GLOAD_LDS16(kpeh + (size_t)(k0 + 64 + trow) * 64 + (d0 - 128) + tcol, buf + 12288 + loff);
                GLOAD_LDS16(kpel + (size_t)(k0 + trow) * 64 + (d0 - 128) + tcol,      buf + 16384 + loff);
                GLOAD_LDS16(kpel + (size_t)(k0 + 64 + trow) * 64 + (d0 - 128) + tcol, buf + 20480 + loff);
            }
            __syncthreads();

            const bf* sQh = (const bf*)buf;
            const bf* sQl = (const bf*)(buf + 4096);
            const bf* sKh = (const bf*)(buf + 8192);
            const bf* sKl = (const bf*)(buf + 16384);
            bf16x8 a_h[4], a_l[4], b_h[2], b_l[2];
#pragma unroll
            for (int mt = 0; mt < 4; mt++) {
                const int r = (mt * 16 + fr) * 32 + quad * 8;
                a_h[mt] = *(const bf16x8*)&sQh[r];
                a_l[mt] = *(const bf16x8*)&sQl[r];
            }
#pragma unroll
            for (int nt = 0; nt < 2; nt++) {
                const int r = (wn + nt * 16 + fr) * 32 + quad * 8;
                b_h[nt] = *(const bf16x8*)&sKh[r];
                b_l[nt] = *(const bf16x8*)&sKl[r];
            }
#pragma unroll
            for (int mt = 0; mt < 4; mt++)
#pragma unroll
                for (int nt = 0; nt < 2; nt++) {
                    S[mt][nt] = __builtin_amdgcn_mfma_f32_16x16x32_bf16(
                        a_l[mt], b_h[nt], S[mt][nt], 0, 0, 0);
                    S[mt][nt] = __builtin_amdgcn_mfma_f32_16x16x32_bf16(
                        a_h[mt], b_l[nt], S[mt][nt], 0, 0, 0);
                    S[mt][nt] = __builtin_amdgcn_mfma_f32_16x16x32_bf16(
                        a_h[mt], b_h[nt], S[mt][nt], 0, 0, 0);
                }
        }

        // ---- online softmax (fp32, block-wide row reductions) ----
#pragma unroll
        for (int mt = 0; mt < 4; mt++)
#pragma unroll
            for (int rr = 0; rr < 4; rr++) {
                const int ri = mt * 16 + quad * 4 + rr;
                const int rowg = q0 + ri;
                float v0 = S[mt][0][rr] * SOFTSCALE;
                float v1 = S[mt][1][rr] * SOFTSCALE;
                if (k0 + wn + fr > rowg)      v0 = -INFINITY;
                if (k0 + wn + 16 + fr > rowg) v1 = -INFINITY;
                S[mt][0][rr] = v0; S[mt][1][rr] = v1;
                float pm = fmaxf(v0, v1);
#pragma unroll
                for (int o = 1; o < 16; o <<= 1) pm = fmaxf(pm, __shfl_xor(pm, o, 64));
                if (fr == 0) redM[ri * 4 + wave] = pm;
            }
        __syncthreads();
#pragma unroll
        for (int mt = 0; mt < 4; mt++)
#pragma unroll
            for (int rr = 0; rr < 4; rr++) {
                const int idx = mt * 4 + rr;
                const int ri = mt * 16 + quad * 4 + rr;
                const float4 g = *(const float4*)&redM[ri * 4];
                const float gm = fmaxf(fmaxf(g.x, g.y), fmaxf(g.z, g.w));
                const float mn = fmaxf(m_i[idx], gm);
                al[idx] = __expf(m_i[idx] - mn);
                m_i[idx] = mn;
                const float p0 = __expf(S[mt][0][rr] - mn);
                const float p1 = __expf(S[mt][1][rr] - mn);
                S[mt][0][rr] = p0; S[mt][1][rr] = p1;   // keep p for PV store
                float ps = p0 + p1;
#pragma unroll
                for (int o = 1; o < 16; o <<= 1) ps += __shfl_xor(ps, o, 64);
                if (fr == 0) redS[ri * 4 + wave] = ps;
            }
#pragma unroll
        for (int mt = 0; mt < 4; mt++)
#pragma unroll
            for (int nt = 0; nt < 2; nt++)
#pragma unroll
                for (int rr = 0; rr < 4; rr++) O[mt][nt][rr] *= al[mt * 4 + rr];
        __syncthreads();
#pragma unroll
        for (int mt = 0; mt < 4; mt++)
#pragma unroll
            for (int rr = 0; rr < 4; rr++) {
                const int idx = mt * 4 + rr;
                const int ri = mt * 16 + quad * 4 + rr;
                const float4 s4 = *(const float4*)&redS[ri * 4];
                l_i[idx] = l_i[idx] * al[idx] + (s4.x + s4.y + s4.z + s4.w);
            }

        // ---- PV: two 64-key halves; both 32-key V chunks preloaded ----
        bf* sVt = (bf*)smem;   // aliases buf0 (dead during PV)
#pragma unroll
        for (int half = 0; half < 2; half++) {
            if (half) __syncthreads();   // prior Ps/sVt readers done
            if ((wave >> 1) == half) {
                const int kc = wn - half * 64;   // 0 or 32
#pragma unroll
                for (int mt = 0; mt < 4; mt++)
#pragma unroll
                    for (int rr = 0; rr < 4; rr++) {
                        const int ri = mt * 16 + quad * 4 + rr;
                        Ps[ri * 72 + kc + fr]      = __float2bfloat16(S[mt][0][rr]);
                        Ps[ri * 72 + kc + 16 + fr] = __float2bfloat16(S[mt][1][rr]);
                    }
            }
            const int kb = k0 + half * 64;
            GLOAD_LDS16(vT + ((size_t)(h * 128 + trow)) * 2048 + kb + tcol,           (char*)sVt + loff);
            GLOAD_LDS16(vT + ((size_t)(h * 128 + 64 + trow)) * 2048 + kb + tcol,      (char*)sVt + 4096 + loff);
            GLOAD_LDS16(vT + ((size_t)(h * 128 + trow)) * 2048 + kb + 32 + tcol,      (char*)sVt + 8192 + loff);
            GLOAD_LDS16(vT + ((size_t)(h * 128 + 64 + trow)) * 2048 + kb + 32 + tcol, (char*)sVt + 12288 + loff);
            __syncthreads();
#pragma unroll
            for (int vc = 0; vc < 2; vc++) {
                bf16x8 ap[4], bv[2];
#pragma unroll
                for (int mt = 0; mt < 4; mt++)
                    ap[mt] = *(const bf16x8*)&Ps[(mt * 16 + fr) * 72 + vc * 32 + quad * 8];
#pragma unroll
                for (int nt = 0; nt < 2; nt++)
                    bv[nt] = *(const bf16x8*)&sVt[vc * 4096 + (wn + nt * 16 + fr) * 32 + quad * 8];
#pragma unroll
                for (int mt = 0; mt < 4; mt++)
#pragma unroll
                    for (int nt = 0; nt < 2; nt++)
                        O[mt][nt] = __builtin_amdgcn_mfma_f32_16x16x32_bf16(
                            ap[mt], bv[nt], O[mt][nt], 0, 0, 0);
            }
        }
    }

    // ---- epilogue: y = O / l (bf16) ----
#pragma unroll
    for (int mt = 0; mt < 4; mt++)
#pragma unroll
        for (int rr = 0; rr < 4; rr++) {
            const float inv = 1.0f / l_i[mt * 4 + rr];
            const int row = q0 + mt * 16 + quad * 4 + rr;
#pragma unroll
            for (int nt = 0; nt < 2; nt++)
                yh[((size_t)row * 16 + h) * 128 + wn + nt * 16 + fr] =
                    __float2bfloat16(O[mt][nt][rr] * inv);
        }
}

// ---------------------------------------------------------------------------
// Workspace (peak < 85 MB):
//  A  @0        : xh(8.39) xl(8.39) -> yh@0, vT@8.39
//  AR @16.78    : (16.78) GEMM temporaries -> woh
//  persistent   : qh@33.55 ql@46.14 knh@58.72 knl@67.11 vh@75.50
//                 kpeh@83.89 kpel@84.15
// ---------------------------------------------------------------------------
extern "C" void kernel_launch(void* const* d_in, const int* in_sizes, int n_in,
                              void* d_out, int out_size, void* d_ws, size_t ws_size,
                              hipStream_t stream)
{
    const float* x        = (const float*)d_in[0];
    const float* freqs    = (const float*)d_in[1];
    const float* wq_a     = (const float*)d_in[3];
    const float* q_norm_w = (const float*)d_in[4];
    const float* wq_b     = (const float*)d_in[5];
    const float* wkv_a    = (const float*)d_in[6];
    const float* kv_norm_w= (const float*)d_in[7];
    const float* wkv_b    = (const float*)d_in[8];
    const float* wo       = (const float*)d_in[9];
    float* out            = (float*)d_out;

    char* ws = (char*)d_ws;
    bf* xh = (bf*)(ws);
    bf* xl = (bf*)(ws + 8388608);
    bf* yh = (bf*)(ws);                   // after x dead
    bf* vT = (bf*)(ws + 8388608);         // after x dead
    char* AR = ws + 16777216;
    bf*    wah    = (bf*)(AR);
    bf*    wal    = (bf*)(AR + 3145728);
    float* qa     = (float*)(AR + 6291456);
    bf*    qah    = (bf*)(AR);
    bf*    qal    = (bf*)(AR + 3145728);
    bf*    wbh    = (bf*)(AR + 6291456);
    bf*    wbl    = (bf*)(AR + 11010048);
    bf*    kah    = (bf*)(AR);
    bf*    kal    = (bf*)(AR + 2359296);
    float* kvfull = (float*)(AR + 4718592);
    bf*    ckvh   = (bf*)(AR + 9437184);
    bf*    ckvl   = (bf*)(AR + 11534336);
    bf*    wvh    = (bf*)(AR);
    bf*    wvl    = (bf*)(AR + 4194304);
    bf*    woh    = (bf*)(AR);
    bf* qh   = (bf*)(ws + 33554432);
    bf* ql   = (bf*)(ws + 46137344);
    bf* knh  = (bf*)(ws + 58720256);
    bf* knl  = (bf*)(ws + 67108864);
    bf* vh   = (bf*)(ws + 75497472);
    bf* kpeh = (bf*)(ws + 83886080);
    bf* kpel = (bf*)(ws + 84148224);

    dim3 blk(256);

    cvt_split<<<4096, blk, 0, stream>>>(x, xh, xl, D_MODEL * D_MODEL);
    cvt_split<<<1536, blk, 0, stream>>>(wq_a, wah, wal, QLORA * D_MODEL);
    gemm_split64<<<dim3(12, 32), blk, 0, stream>>>(
        xh, xl, wah, wal, qa, T_DIM, QLORA, D_MODEL);
    rmsnorm_cvt<<<T_DIM, blk, 0, stream>>>(qa, QLORA, QLORA, q_norm_w, qah, qal);
    cvt_split<<<2304, blk, 0, stream>>>(wq_b, wbh, wbl, 3072 * QLORA);
    gemm_split<1><<<dim3(24, 16), blk, 0, stream>>>(
        qah, qal, wbh, wbl, freqs, nullptr, qh, ql, nullptr,
        T_DIM, 3072, QLORA);
    cvt_split<<<1152, blk, 0, stream>>>(wkv_a, kah, kal, KVFULL_D * D_MODEL);
    gemm_split64<<<dim3(9, 32), blk, 0, stream>>>(
        xh, xl, kah, kal, kvfull, T_DIM, KVFULL_D, D_MODEL);
    rope_k_cvt<<<256, blk, 0, stream>>>(kvfull, freqs, kpeh, kpel);
    rmsnorm_cvt<<<T_DIM, blk, 0, stream>>>(kvfull, KVFULL_D, KVLORA, kv_norm_w, ckvh, ckvl);
    cvt_split<<<2048, blk, 0, stream>>>(wkv_b, wvh, wvl, 4096 * KVLORA);
    gemm_split<2><<<dim3(32, 16), blk, 0, stream>>>(
        ckvh, ckvl, wvh, wvl, nullptr, nullptr, knh, knl, vh,
        T_DIM, 4096, KVLORA);
    transpose_v<<<dim3(64, 4, 16), blk, 0, stream>>>(vh, vT);
    attn_mfma<<<dim3(512), blk, 0, stream>>>(
        qh, ql, knh, knl, kpeh, kpel, vT, yh);
    cvt_hi<<<4096, blk, 0, stream>>>(wo, woh, D_MODEL * D_MODEL);
    gemm_bf16<<<dim3(16, 16), blk, 0, stream>>>(
        yh, woh, out, T_DIM, D_MODEL, D_MODEL);
}